// Round 6
// baseline (158.453 us; speedup 1.0000x reference)
//
#include <hip/hip_runtime.h>
#include <math.h>

typedef _Float16 f16;
typedef __attribute__((ext_vector_type(2))) _Float16 f16x2;
typedef __attribute__((ext_vector_type(4))) _Float16 f16x4;
typedef __attribute__((ext_vector_type(8))) _Float16 f16x8;
typedef __attribute__((ext_vector_type(4))) float f32x4;

#define NBATCH 8
#define WSA_ELE 36864      // 32*1152 w_off, k-major, frag-swizzled
#define WSB_ELE 147456     // 128*1152 w_def, k-major, frag-swizzled
#define WPREP_BLOCKS 720   // (WSA_ELE + WSB_ELE) / 256
#define XPREP_BLOCKS 512   // transpose blocks
#define OPREP_BLOCKS 1024  // out bias-init blocks (4096 f32 each)
// workspace byte offsets
#define OFF_WSB  73728
#define OFF_XT   368640

__device__ __forceinline__ void gload_lds16(const f16* gsrc, f16* ldst) {
  // per-lane global src; wave-uniform LDS base (HW adds lane*16)
  __builtin_amdgcn_global_load_lds(
      (const __attribute__((address_space(1))) unsigned int*)gsrc,
      (__attribute__((address_space(3))) unsigned int*)ldst, 16, 0, 0);
}

// ---- prep: weights->fp16 frag-swizzled + x NCHW->NHWC fp16 + out=bias ----
// swizzled element e = ((ch*NFRAG + mt)*64 + lane)*8 + j holds
// W[row = mt*16 + (lane&15)][kidx = ch*32 + (lane>>4)*8 + j], kidx = k*128 + cc.
__global__ __launch_bounds__(256) void prep_kernel(const float* __restrict__ x,
                                                   const float* __restrict__ w_off,
                                                   const float* __restrict__ w_def,
                                                   const float* __restrict__ b_def,
                                                   f16* __restrict__ wsA,
                                                   f16* __restrict__ wsB,
                                                   f16* __restrict__ xt,
                                                   float* __restrict__ out) {
  __shared__ f16 s_t[128 * 66];
  const int bid = blockIdx.x;
  const int t = threadIdx.x;
  if (bid < WPREP_BLOCKS) {
    int i = bid * 256 + t;
    if (i < WSA_ELE) {
      int j = i & 7, lane = (i >> 3) & 63, fm = i >> 9;
      int ch = fm >> 1, mt = fm & 1;
      int row = mt * 16 + (lane & 15);
      int kidx = ch * 32 + (lane >> 4) * 8 + j;
      int k = kidx >> 7, cc = kidx & 127;
      float v = (row < 27) ? w_off[row * 1152 + cc * 9 + k] : 0.0f;
      wsA[i] = (f16)v;
    } else {
      int e = i - WSA_ELE;
      int j = e & 7, lane = (e >> 3) & 63, fm = e >> 9;
      int ch = fm >> 3, mt = fm & 7;
      int row = mt * 16 + (lane & 15);
      int kidx = ch * 32 + (lane >> 4) * 8 + j;
      int k = kidx >> 7, cc = kidx & 127;
      wsB[e] = (f16)w_def[row * 1152 + cc * 9 + k];
    }
  } else if (bid < WPREP_BLOCKS + XPREP_BLOCKS) {
    const int bb = bid - WPREP_BLOCKS;
    const int b = bb >> 6;
    const int pos0 = (bb & 63) << 6;
    const float* xb = x + ((size_t)b << 19);
    for (int i = t; i < 8192; i += 256) {
      int c = i >> 6, p = i & 63;
      s_t[c * 66 + p] = (f16)xb[c * 4096 + pos0 + p];
    }
    __syncthreads();
    f16* xtb = xt + ((size_t)b << 19);
    for (int i = t; i < 4096; i += 256) {
      int p = i >> 6, c2 = (i & 63) * 2;
      unsigned v0 = *(const unsigned short*)&s_t[c2 * 66 + p];
      unsigned v1 = *(const unsigned short*)&s_t[(c2 + 1) * 66 + p];
      *(unsigned*)&xtb[(size_t)(pos0 + p) * 128 + c2] = v0 | (v1 << 16);
    }
  } else {
    const int ob = bid - (WPREP_BLOCKS + XPREP_BLOCKS);   // one 4096-f32 plane
    const float bv = b_def[ob & 127];
    float4 v = {bv, bv, bv, bv};
    float4* p = (float4*)(out + (size_t)ob * 4096 + t * 16);
    p[0] = v; p[1] = v; p[2] = v; p[3] = v;
  }
}

// ---- fused DCNv2: offset conv -> table -> K-split MFMA GEMM, atomic out ----
// grid 1024: bid = half*512 + b*64 + ho. Half h covers K-chunks [h*18, h*18+18)
// (tap range k in [h*4, h*4+4]); each block recomputes the full offset conv.
__global__ __launch_bounds__(256, 4) void dcn_fused_kernel(const f16* __restrict__ xt,
                                                           const f16* __restrict__ wsA,
                                                           const f16* __restrict__ wsB,
                                                           const float* __restrict__ b_off,
                                                           const float* __restrict__ b_def,
                                                           float* __restrict__ out) {
  __shared__ __align__(16) f16 s_a[8192];   // 16 KB A buffer; phase1/2 alias as s_off
  __shared__ ushort4 s_pos[5 * 64];         // 2560 B corner positions (half's taps)
  __shared__ f16x4   s_wth[5 * 64];         // 2560 B modulated weights
  const int bid = blockIdx.x;
  const int half = bid >> 9;
  const int b = (bid >> 6) & 7, ho = bid & 63;
  const int t = threadIdx.x, lane = t & 63, wid = t >> 6;
  const int q = lane >> 4, li = lane & 15;
  const int px = (wid << 4) + li;
  const char* xtb = (const char*)xt + ((size_t)b << 20);
  float* s_off = (float*)s_a;               // 27*65 f32 = 7020 B, alias

  // ---- Phase 1: offset conv (full K=1152), barrier-free, A-frags from L2 ----
  f32x4 oa0 = {0.f, 0.f, 0.f, 0.f}, oa1 = {0.f, 0.f, 0.f, 0.f};
  for (int k = 0; k < 9; ++k) {
    const int ky = k / 3, kx = k - ky * 3;
    const int y = ho + ky - 1;
    const int xx = px + kx - 1;
    const bool valid = ((unsigned)y < 64u) && ((unsigned)xx < 64u);
    const int pos = min(max(y, 0), 63) * 64 + min(max(xx, 0), 63);
    const int voff = pos * 256 + q * 16;
    #pragma unroll
    for (int c4 = 0; c4 < 4; ++c4) {
      union { uint4 u; f16x8 v; } bu;
      bu.u = *(const uint4*)(xtb + voff + c4 * 64);
      if (!valid) { bu.u.x = 0u; bu.u.y = 0u; bu.u.z = 0u; bu.u.w = 0u; }
      const int ch = k * 4 + c4;
      f16x8 a0 = *(const f16x8*)&wsA[(ch * 2    ) * 512 + lane * 8];
      f16x8 a1 = *(const f16x8*)&wsA[(ch * 2 + 1) * 512 + lane * 8];
      oa0 = __builtin_amdgcn_mfma_f32_16x16x32_f16(a0, bu.v, oa0, 0, 0, 0);
      oa1 = __builtin_amdgcn_mfma_f32_16x16x32_f16(a1, bu.v, oa1, 0, 0, 0);
    }
  }
  #pragma unroll
  for (int mt = 0; mt < 2; ++mt) {
    f32x4 a = mt ? oa1 : oa0;
    #pragma unroll
    for (int r = 0; r < 4; ++r) {
      int oc = mt * 16 + q * 4 + r;
      if (oc < 27) {
        float v = a[r] + b_off[oc];
        if (oc >= 18) v = 1.0f / (1.0f + __expf(-v));
        s_off[oc * 65 + px] = v;   // stride 65: conflict-spread
      }
    }
  }
  __syncthreads();

  // ---- Phase 2: bilinear table for this half's 5 taps ----
  const int klo = half * 4;
  for (int f = t; f < 320; f += 256) {
    int kk = f >> 6, p = f & 63;
    int k = klo + kk;
    int ky = k / 3, kx = k - ky * 3;
    float oy = s_off[(2 * k    ) * 65 + p];
    float ox = s_off[(2 * k + 1) * 65 + p];
    float m  = s_off[(18 + k   ) * 65 + p];
    float py  = oy + (float)(ho + ky - 1);
    float pxf = ox + (float)(p + kx - 1);
    float y0f = floorf(py), x0f = floorf(pxf);
    float wy = py - y0f, wx = pxf - x0f;
    int y0 = (int)y0f, x0 = (int)x0f;
    int y1 = y0 + 1, x1 = x0 + 1;
    bool y0v = (unsigned)y0 < 64u, y1v = (unsigned)y1 < 64u;
    bool x0v = (unsigned)x0 < 64u, x1v = (unsigned)x1 < 64u;
    int y0c = min(max(y0, 0), 63), y1c = min(max(y1, 0), 63);
    int x0c = min(max(x0, 0), 63), x1c = min(max(x1, 0), 63);
    ushort4 p4;
    p4.x = (unsigned short)(y0c * 64 + x0c);
    p4.y = (unsigned short)(y0c * 64 + x1c);
    p4.z = (unsigned short)(y1c * 64 + x0c);
    p4.w = (unsigned short)(y1c * 64 + x1c);
    f16x4 wh;
    wh[0] = (f16)((y0v && x0v) ? (1.f - wy) * (1.f - wx) * m : 0.f);
    wh[1] = (f16)((y0v && x1v) ? (1.f - wy) * wx         * m : 0.f);
    wh[2] = (f16)((y1v && x0v) ? wy         * (1.f - wx) * m : 0.f);
    wh[3] = (f16)((y1v && x1v) ? wy         * wx         * m : 0.f);
    s_pos[f] = p4;
    s_wth[f] = wh;
  }
  // (first loop barrier below covers: table visible + s_off reads done before s_a reuse)

  // ---- Phase 3: 18 K-chunks, reg-sampled B + LDS-staged A ----
  f32x4 acc[8];
  #pragma unroll
  for (int mt = 0; mt < 8; ++mt) acc[mt] = (f32x4){0.f, 0.f, 0.f, 0.f};

  const int cg0 = half * 18;
  for (int s = 0; s < 18; ++s) {
    const int c4g = cg0 + s;
    const int k = c4g >> 2, c4 = c4g & 3, sub = s & 1;
    if (sub == 0) {
      __syncthreads();   // prior chunk reads done / phase-2 done (s==0)
      const f16* src = wsB + c4g * 4096 + wid * 2048 + lane * 8;
      f16* dst = &s_a[wid * 2048];
      gload_lds16(src,        dst);
      gload_lds16(src +  512, dst +  512);
      gload_lds16(src + 1024, dst + 1024);
      gload_lds16(src + 1536, dst + 1536);
      __syncthreads();   // staging drained (vmcnt(0) before barrier)
    }
    const int e = (k - klo) * 64 + px;
    const ushort4 p4 = s_pos[e];
    const f16x4   w4 = s_wth[e];
    const unsigned cb = (unsigned)(c4 * 64 + q * 16);
    union { uint4 u; f16x2 h[4]; } d0, d1, d2, d3;
    d0.u = *(const uint4*)(xtb + (((unsigned)p4.x << 8) + cb));
    d1.u = *(const uint4*)(xtb + (((unsigned)p4.y << 8) + cb));
    d2.u = *(const uint4*)(xtb + (((unsigned)p4.z << 8) + cb));
    d3.u = *(const uint4*)(xtb + (((unsigned)p4.w << 8) + cb));
    const f16x2 wp0 = {w4[0], w4[0]}, wp1 = {w4[1], w4[1]};
    const f16x2 wp2 = {w4[2], w4[2]}, wp3 = {w4[3], w4[3]};
    union { f16x2 h[4]; f16x8 v; } bf;
    #pragma unroll
    for (int i = 0; i < 4; ++i) {
      f16x2 sm = d0.h[i] * wp0;
      sm = sm + d1.h[i] * wp1;
      sm = sm + d2.h[i] * wp2;
      sm = sm + d3.h[i] * wp3;
      bf.h[i] = sm;
    }
    const f16* ab = &s_a[sub * 4096];
    #pragma unroll
    for (int mt = 0; mt < 8; ++mt) {
      f16x8 a = *(const f16x8*)&ab[(mt * 64 + lane) * 8];
      acc[mt] = __builtin_amdgcn_mfma_f32_16x16x32_f16(a, bf.v, acc[mt], 0, 0, 0);
    }
  }

  // ---- Phase 4: atomic accumulate into bias-pre-initialized out ----
  float* o = out + ((size_t)b << 19) + ho * 64 + px;
  #pragma unroll
  for (int mt = 0; mt < 8; ++mt) {
    #pragma unroll
    for (int r = 0; r < 4; ++r) {
      int oc = mt * 16 + q * 4 + r;
      atomicAdd(o + oc * 4096, acc[mt][r]);
    }
  }
}

extern "C" void kernel_launch(void* const* d_in, const int* in_sizes, int n_in,
                              void* d_out, int out_size, void* d_ws, size_t ws_size,
                              hipStream_t stream) {
  const float* x     = (const float*)d_in[0];
  const float* w_off = (const float*)d_in[1];
  const float* b_off = (const float*)d_in[2];
  const float* w_def = (const float*)d_in[3];
  const float* b_def = (const float*)d_in[4];
  float* out = (float*)d_out;

  f16* wsA = (f16*)d_ws;
  f16* wsB = (f16*)((char*)d_ws + OFF_WSB);
  f16* xt  = (f16*)((char*)d_ws + OFF_XT);

  prep_kernel<<<dim3(WPREP_BLOCKS + XPREP_BLOCKS + OPREP_BLOCKS), dim3(256), 0, stream>>>(
      x, w_off, w_def, b_def, wsA, wsB, xt, out);
  dcn_fused_kernel<<<dim3(2 * NBATCH * 64), dim3(256), 0, stream>>>(
      xt, wsA, wsB, b_off, b_def, out);
}